// Round 1
// baseline (1754.738 us; speedup 1.0000x reference)
//
#include <hip/hip_runtime.h>
#include <hip/hip_bf16.h>

// Problem constants (from reference):
// B=2, S=2048, D=1024, H=16, d_k=64, WINDOW=256
// Outputs (concatenated in d_out): out [B,S,D] fp32, attn [B,H,S,S] fp32.
// Workspace layout (fp32): Qp | Kp | Vp | AO, each B*S*D = 4,194,304 floats (16 MB).
// Total ws use = 64 MB.

constexpr int Bb   = 2;
constexpr int Ss   = 2048;
constexpr int Dd   = 1024;
constexpr int Hh   = 16;
constexpr int DKk  = 64;
constexpr int WINw = 256;

__device__ inline float dot4f(float4 a, float4 b) {
  return fmaf(a.x, b.x, fmaf(a.y, b.y, fmaf(a.z, b.z, a.w * b.w)));
}

// ---------------------------------------------------------------------------
// GEMM: C[4096,1024] = A[4096,1024] @ W[1024,1024] + bias
// 128x128 tile, BK=16, 256 threads, 8x8 micro-tile split as 2x2 blocks of 4x4
// (keeps every LDS b128 read at <=2-way bank aliasing, which is free).
// ---------------------------------------------------------------------------
__global__ __launch_bounds__(256) void gemm_kernel(
    const float* __restrict__ A, const float* __restrict__ W,
    const float* __restrict__ bias, float* __restrict__ C) {
  __shared__ float As[16][132];  // [k][m], row stride 132 floats = 528 B (16B mult)
  __shared__ float Ws[16][132];  // [k][n]
  const int t = threadIdx.x;
  const int bm = blockIdx.y * 128;
  const int bn = blockIdx.x * 128;
  const int tx = t & 15;   // n micro index
  const int ty = t >> 4;   // m micro index
  float acc[2][2][4][4] = {};

  for (int k0 = 0; k0 < 1024; k0 += 16) {
    // A tile 128x16 -> As[k][m] (transposed store, scalar writes, 2-way max)
#pragma unroll
    for (int i = 0; i < 2; ++i) {
      int f = t + i * 256;
      int r = f >> 2;              // 0..127
      int c4 = (f & 3) << 2;       // 0,4,8,12
      float4 a = *(const float4*)&A[(size_t)(bm + r) * 1024 + k0 + c4];
      As[c4 + 0][r] = a.x; As[c4 + 1][r] = a.y;
      As[c4 + 2][r] = a.z; As[c4 + 3][r] = a.w;
    }
    // W tile 16x128 -> Ws[k][n] (aligned float4 stores)
#pragma unroll
    for (int i = 0; i < 2; ++i) {
      int f = t + i * 256;
      int rw = f >> 5;             // 0..15
      int cw4 = (f & 31) << 2;     // 0..124
      *(float4*)&Ws[rw][cw4] =
          *(const float4*)&W[(size_t)(k0 + rw) * 1024 + bn + cw4];
    }
    __syncthreads();
#pragma unroll
    for (int kk = 0; kk < 16; ++kk) {
      float4 a0 = *(const float4*)&As[kk][ty * 4];
      float4 a1 = *(const float4*)&As[kk][ty * 4 + 64];
      float4 w0 = *(const float4*)&Ws[kk][tx * 4];
      float4 w1 = *(const float4*)&Ws[kk][tx * 4 + 64];
      float av[2][4] = {{a0.x, a0.y, a0.z, a0.w}, {a1.x, a1.y, a1.z, a1.w}};
      float wv[2][4] = {{w0.x, w0.y, w0.z, w0.w}, {w1.x, w1.y, w1.z, w1.w}};
#pragma unroll
      for (int ia = 0; ia < 2; ++ia)
#pragma unroll
        for (int iw = 0; iw < 2; ++iw)
#pragma unroll
          for (int i = 0; i < 4; ++i)
#pragma unroll
            for (int j = 0; j < 4; ++j)
              acc[ia][iw][i][j] =
                  fmaf(av[ia][i], wv[iw][j], acc[ia][iw][i][j]);
    }
    __syncthreads();
  }

#pragma unroll
  for (int ia = 0; ia < 2; ++ia)
#pragma unroll
    for (int i = 0; i < 4; ++i) {
      int row = bm + ia * 64 + ty * 4 + i;
#pragma unroll
      for (int iw = 0; iw < 2; ++iw) {
        int col = bn + iw * 64 + tx * 4;
        float4 bv = *(const float4*)&bias[col];
        float4 o;
        o.x = acc[ia][iw][i][0] + bv.x;
        o.y = acc[ia][iw][i][1] + bv.y;
        o.z = acc[ia][iw][i][2] + bv.z;
        o.w = acc[ia][iw][i][3] + bv.w;
        *(float4*)&C[(size_t)row * 1024 + col] = o;
      }
    }
}

// ---------------------------------------------------------------------------
// Scores: for each (b,h) and 32-query tile, compute banded Q.K^T / 8 and
// scatter the in-band raw scores into the attn output region (later kernels
// normalize in place). Q rows persist in registers (2 rows / thread);
// K is read straight from global (4 distinct rows per wave -> broadcast).
// ---------------------------------------------------------------------------
__global__ __launch_bounds__(256) void score_kernel(
    const float* __restrict__ Qp, const float* __restrict__ Kp,
    float* __restrict__ attn) {
  const int nqt = Ss / 32;  // 64
  int bid = blockIdx.x;     // 2048
  int qt = bid % nqt;
  int h  = (bid / nqt) % Hh;
  int b  = bid / (nqt * Hh);
  int q0 = qt * 32;
  int jlo = q0 - WINw; if (jlo < 0) jlo = 0;
  int jhi = q0 + 31 + WINw; if (jhi > Ss - 1) jhi = Ss - 1;

  const int t  = threadIdx.x;
  const int qa = t & 15;   // query pair id: rows q0+qa, q0+qa+16
  const int kq = t >> 4;   // key quad id: keys jc + kq*4 .. +3

  float4 qreg0[16], qreg1[16];
  const float* qb0 = &Qp[((size_t)(b * Ss + q0 + qa)) * Dd + h * DKk];
  const float* qb1 = qb0 + (size_t)16 * Dd;
#pragma unroll
  for (int i = 0; i < 16; ++i) {
    qreg0[i] = *(const float4*)&qb0[i * 4];
    qreg1[i] = *(const float4*)&qb1[i * 4];
  }

  const int qA = q0 + qa, qB = qA + 16;
  float* arow0 = attn + ((size_t)((b * Hh + h) * Ss + qA)) * Ss;
  float* arow1 = arow0 + (size_t)16 * Ss;

  for (int jc = jlo; jc <= jhi; jc += 64) {
    float s0[4] = {0.f, 0.f, 0.f, 0.f};
    float s1[4] = {0.f, 0.f, 0.f, 0.f};
    // NOTE: rows jc+kq*4+kk can run past jhi; reads stay inside the ws slabs
    // (benign garbage), and the store mask discards those lanes.
    const float* kb = &Kp[((size_t)(b * Ss + jc + kq * 4)) * Dd + h * DKk];
#pragma unroll
    for (int d4 = 0; d4 < 16; ++d4) {
      float4 k0v = *(const float4*)&kb[d4 * 4];
      float4 k1v = *(const float4*)&kb[(size_t)Dd + d4 * 4];
      float4 k2v = *(const float4*)&kb[(size_t)2 * Dd + d4 * 4];
      float4 k3v = *(const float4*)&kb[(size_t)3 * Dd + d4 * 4];
      float4 q0v = qreg0[d4];
      float4 q1v = qreg1[d4];
      s0[0] += dot4f(q0v, k0v); s0[1] += dot4f(q0v, k1v);
      s0[2] += dot4f(q0v, k2v); s0[3] += dot4f(q0v, k3v);
      s1[0] += dot4f(q1v, k0v); s1[1] += dot4f(q1v, k1v);
      s1[2] += dot4f(q1v, k2v); s1[3] += dot4f(q1v, k3v);
    }
#pragma unroll
    for (int kk = 0; kk < 4; ++kk) {
      int j = jc + kq * 4 + kk;
      if (j < Ss) {
        if (j >= qA - WINw && j <= qA + WINw) arow0[j] = s0[kk] * 0.125f;
        if (j >= qB - WINw && j <= qB + WINw) arow1[j] = s1[kk] * 0.125f;
      }
    }
  }
}

// ---------------------------------------------------------------------------
// Softmax: one wave per attn row. Reads the banded raw scores (aligned 64-col
// slots kept in registers), computes max / sum(exp), writes the FULL 2048-wide
// row: normalized probs in band, exact zeros elsewhere. No LDS, no barriers.
// ---------------------------------------------------------------------------
__global__ __launch_bounds__(256) void softmax_rows(float* __restrict__ attn) {
  const int wv = threadIdx.x >> 6;
  const int lane = threadIdx.x & 63;
  const int row = blockIdx.x * 4 + wv;  // 0 .. B*H*S-1
  const int q = row & (Ss - 1);
  float* arow = attn + (size_t)row * Ss;
  int lo = q - WINw; if (lo < 0) lo = 0;
  int hi = q + WINw; if (hi > Ss - 1) hi = Ss - 1;
  const int k0 = lo >> 6, kn = hi >> 6;  // aligned 64-wide slots (<=10)

  float sreg[10];
  float m = -1e30f;
#pragma unroll
  for (int k = 0; k < 10; ++k) {
    int w = k0 + k;
    int j = (w << 6) + lane;
    bool inb = (w <= kn) && (j >= lo) && (j <= hi);
    float vv = inb ? arow[j] : -1e30f;
    sreg[k] = vv;
    m = fmaxf(m, vv);
  }
#pragma unroll
  for (int off = 32; off > 0; off >>= 1) m = fmaxf(m, __shfl_xor(m, off, 64));

  float e[10];
  float l = 0.f;
#pragma unroll
  for (int k = 0; k < 10; ++k) {
    e[k] = __expf(sreg[k] - m);  // masked slots: exp(-huge) == 0
    l += e[k];
  }
#pragma unroll
  for (int off = 32; off > 0; off >>= 1) l += __shfl_xor(l, off, 64);
  float inv = 1.f / l;

  // in-band slots
#pragma unroll
  for (int k = 0; k < 10; ++k) {
    int w = k0 + k;
    if (w <= kn) {
      int j = (w << 6) + lane;
      arow[j] = (j >= lo && j <= hi) ? e[k] * inv : 0.f;
    }
  }
  // zero everything outside [k0, kn]
  for (int w = 0; w < Ss / 64; ++w) {
    if (w < k0 || w > kn) arow[(w << 6) + lane] = 0.f;
  }
}

// ---------------------------------------------------------------------------
// PV: out[q][d] = sum_j P[q][j] * V[j][d] over the band. P is read from the
// (already normalized, zero-padded) attn rows -> no masking needed. No LDS:
// both P and V come through L1/L2 with in-wave broadcast. 2 queries x 4 dims
// per thread, 4 keys per inner step -> 32 FMA per 6 loads.
// ---------------------------------------------------------------------------
__global__ __launch_bounds__(256) void pv_kernel(
    const float* __restrict__ attn, const float* __restrict__ Vp,
    float* __restrict__ AO) {
  const int nqt = Ss / 32;  // 64
  int bid = blockIdx.x;     // 2048
  int qt = bid % nqt;
  int h  = (bid / nqt) % Hh;
  int b  = bid / (nqt * Hh);
  int q0 = qt * 32;
  int jlo = q0 - WINw; if (jlo < 0) jlo = 0;
  int jhi = q0 + 31 + WINw; if (jhi > Ss - 1) jhi = Ss - 1;

  const int t = threadIdx.x;
  const int dg = t & 15;   // dims dg*4..+3
  const int qp = t >> 4;   // rows q0+qp and q0+qp+16

  const float* arow0 = attn + ((size_t)((b * Hh + h) * Ss + q0 + qp)) * Ss;
  const float* arow1 = arow0 + (size_t)16 * Ss;
  float4 acc0 = {0.f, 0.f, 0.f, 0.f};
  float4 acc1 = {0.f, 0.f, 0.f, 0.f};

  for (int jc = jlo; jc <= jhi; jc += 64) {
    int lim = Ss - jc; if (lim > 64) lim = 64;  // stay inside the row
    for (int jj = 0; jj < lim; jj += 4) {
      int j = jc + jj;
      float4 p0 = *(const float4*)&arow0[j];
      float4 p1 = *(const float4*)&arow1[j];
      const float* vbase = &Vp[((size_t)(b * Ss + j)) * Dd + h * DKk + dg * 4];
      float4 v0 = *(const float4*)(vbase);
      float4 v1 = *(const float4*)(vbase + Dd);
      float4 v2 = *(const float4*)(vbase + 2 * Dd);
      float4 v3 = *(const float4*)(vbase + 3 * Dd);
      acc0.x = fmaf(p0.x, v0.x, fmaf(p0.y, v1.x, fmaf(p0.z, v2.x, fmaf(p0.w, v3.x, acc0.x))));
      acc0.y = fmaf(p0.x, v0.y, fmaf(p0.y, v1.y, fmaf(p0.z, v2.y, fmaf(p0.w, v3.y, acc0.y))));
      acc0.z = fmaf(p0.x, v0.z, fmaf(p0.y, v1.z, fmaf(p0.z, v2.z, fmaf(p0.w, v3.z, acc0.z))));
      acc0.w = fmaf(p0.x, v0.w, fmaf(p0.y, v1.w, fmaf(p0.z, v2.w, fmaf(p0.w, v3.w, acc0.w))));
      acc1.x = fmaf(p1.x, v0.x, fmaf(p1.y, v1.x, fmaf(p1.z, v2.x, fmaf(p1.w, v3.x, acc1.x))));
      acc1.y = fmaf(p1.x, v0.y, fmaf(p1.y, v1.y, fmaf(p1.z, v2.y, fmaf(p1.w, v3.y, acc1.y))));
      acc1.z = fmaf(p1.x, v0.z, fmaf(p1.y, v1.z, fmaf(p1.z, v2.z, fmaf(p1.w, v3.z, acc1.z))));
      acc1.w = fmaf(p1.x, v0.w, fmaf(p1.y, v1.w, fmaf(p1.z, v2.w, fmaf(p1.w, v3.w, acc1.w))));
    }
  }

  float* o0 = &AO[((size_t)(b * Ss + q0 + qp)) * Dd + h * DKk + dg * 4];
  *(float4*)o0 = acc0;
  *(float4*)(o0 + (size_t)16 * Dd) = acc1;
}

// ---------------------------------------------------------------------------
extern "C" void kernel_launch(void* const* d_in, const int* in_sizes, int n_in,
                              void* d_out, int out_size, void* d_ws, size_t ws_size,
                              hipStream_t stream) {
  const float* q  = (const float*)d_in[0];
  const float* k  = (const float*)d_in[1];
  const float* v  = (const float*)d_in[2];
  const float* Wq = (const float*)d_in[3];
  const float* bq = (const float*)d_in[4];
  const float* Wk = (const float*)d_in[5];
  const float* bk = (const float*)d_in[6];
  const float* Wv = (const float*)d_in[7];
  const float* bv = (const float*)d_in[8];
  const float* Wo = (const float*)d_in[9];
  const float* bo = (const float*)d_in[10];

  float* out  = (float*)d_out;
  float* attn = out + (size_t)Bb * Ss * Dd;  // 4,194,304 floats in

  const size_t slab = (size_t)Bb * Ss * Dd;  // 4,194,304 floats
  float* Qp = (float*)d_ws;
  float* Kp = Qp + slab;
  float* Vp = Kp + slab;
  float* AO = Vp + slab;

  dim3 gg(8, 32), bb(256);
  hipLaunchKernelGGL(gemm_kernel, gg, bb, 0, stream, q, Wq, bq, Qp);
  hipLaunchKernelGGL(gemm_kernel, gg, bb, 0, stream, k, Wk, bk, Kp);
  hipLaunchKernelGGL(gemm_kernel, gg, bb, 0, stream, v, Wv, bv, Vp);
  hipLaunchKernelGGL(score_kernel,  dim3(Bb * Hh * (Ss / 32)), bb, 0, stream, Qp, Kp, attn);
  hipLaunchKernelGGL(softmax_rows,  dim3(Bb * Hh * Ss / 4),    bb, 0, stream, attn);
  hipLaunchKernelGGL(pv_kernel,     dim3(Bb * Hh * (Ss / 32)), bb, 0, stream, attn, Vp, AO);
  hipLaunchKernelGGL(gemm_kernel, gg, bb, 0, stream, AO, Wo, bo, out);
}

// Round 2
// 1392.434 us; speedup vs baseline: 1.2602x; 1.2602x over previous
//
#include <hip/hip_runtime.h>

// B=2, S=2048, D=1024, H=16, d_k=64, WINDOW=256
// d_out = out [B,S,D] fp32  ++  attn [B,H,S,S] fp32
// ws (128 MB): Xs bf16 3x[4096x2048] | Wt bf16 4x[1024x2048] | Qp,Kp,Vp f32 | AO f32

constexpr int Bb = 2, Ss = 2048, Dd = 1024, Hh = 16, WINw = 256;
constexpr size_t XS_SLAB = (size_t)4096 * 2048;  // bf16 elems
constexpr size_t WT_SLAB = (size_t)1024 * 2048;  // bf16 elems
constexpr size_t F_SLAB  = (size_t)4096 * 1024;  // f32 elems

typedef short s16x8 __attribute__((ext_vector_type(8)));
typedef float f32x4 __attribute__((ext_vector_type(4)));

__device__ inline unsigned short f2bf(float x) {
  unsigned u = __float_as_uint(x);
  u += 0x7fff + ((u >> 16) & 1);  // RNE
  return (unsigned short)(u >> 16);
}
__device__ inline float bf2f(unsigned short h) {
  return __uint_as_float(((unsigned)h) << 16);
}

// ---------------------------------------------------------------------------
// fp32 [4096x1024] -> bf16 split [4096x2048] = [hi | lo]; z selects source.
// ---------------------------------------------------------------------------
__global__ __launch_bounds__(256) void convert_x(
    const float* __restrict__ x0, const float* __restrict__ x1,
    const float* __restrict__ x2, unsigned short* __restrict__ Xs) {
  int z = blockIdx.z;
  const float* src = z == 0 ? x0 : (z == 1 ? x1 : x2);
  unsigned short* dst = Xs + (size_t)z * XS_SLAB;
  size_t idx = ((size_t)blockIdx.x * 256 + threadIdx.x) * 4;
  int r = (int)(idx >> 10);
  int c = (int)(idx & 1023);
  f32x4 v = *(const f32x4*)&src[idx];
  unsigned short hi[4], lo[4];
#pragma unroll
  for (int i = 0; i < 4; ++i) {
    float vi = v[i];
    hi[i] = f2bf(vi);
    lo[i] = f2bf(vi - bf2f(hi[i]));
  }
  ushort4 h4 = {hi[0], hi[1], hi[2], hi[3]};
  ushort4 l4 = {lo[0], lo[1], lo[2], lo[3]};
  *(ushort4*)&dst[(size_t)r * 2048 + c] = h4;
  *(ushort4*)&dst[(size_t)r * 2048 + 1024 + c] = l4;
}

// ---------------------------------------------------------------------------
// W [1024x1024] fp32 -> Wt bf16 [n][2048] = [W_hi^T | W_lo^T] (transposed).
// ---------------------------------------------------------------------------
__global__ __launch_bounds__(256) void convert_w(
    const float* __restrict__ w0, const float* __restrict__ w1,
    const float* __restrict__ w2, const float* __restrict__ w3,
    unsigned short* __restrict__ Wt) {
  __shared__ float T[64][65];
  int z = blockIdx.z;
  const float* W = z == 0 ? w0 : (z == 1 ? w1 : (z == 2 ? w2 : w3));
  unsigned short* dst = Wt + (size_t)z * WT_SLAB;
  int k0 = blockIdx.y * 64, n0 = blockIdx.x * 64;
  int t = threadIdx.x;
#pragma unroll
  for (int i = 0; i < 4; ++i) {
    int row = (t >> 4) + i * 16;
    int c4 = (t & 15) * 4;
    f32x4 v = *(const f32x4*)&W[(size_t)(k0 + row) * 1024 + n0 + c4];
    T[row][c4 + 0] = v[0]; T[row][c4 + 1] = v[1];
    T[row][c4 + 2] = v[2]; T[row][c4 + 3] = v[3];
  }
  __syncthreads();
  int n = t >> 2;
  int kc = (t & 3) * 16;
  unsigned short hi[16], lo[16];
#pragma unroll
  for (int j = 0; j < 16; ++j) {
    float x = T[kc + j][n];
    hi[j] = f2bf(x);
    lo[j] = f2bf(x - bf2f(hi[j]));
  }
  size_t base = (size_t)(n0 + n) * 2048 + k0 + kc;
#pragma unroll
  for (int j4 = 0; j4 < 4; ++j4) {
    ushort4 h4 = {hi[j4 * 4], hi[j4 * 4 + 1], hi[j4 * 4 + 2], hi[j4 * 4 + 3]};
    ushort4 l4 = {lo[j4 * 4], lo[j4 * 4 + 1], lo[j4 * 4 + 2], lo[j4 * 4 + 3]};
    *(ushort4*)&dst[base + j4 * 4] = h4;
    *(ushort4*)&dst[base + 1024 + j4 * 4] = l4;
  }
}

// ---------------------------------------------------------------------------
// C[4096x1024] = Abig[4096x3072] @ Wbig[3072x1024] + bias, via bf16x3 split:
// Abig cols: [0,1k)->A_hi, [1k,2k)->A_hi, [2k,3k)->A_lo  (phys col = kb<1024?kb:kb-1024)
// Wbig rows: [0,1k)->W_hi, [1k,2k)->W_lo, [2k,3k)->W_hi  (phys col = kb<2048?kb:kb-2048)
// 128x128 tile, BK=32, 4 waves each 64x64 = 4x4 of mfma_f32_16x16x32_bf16.
// LDS slots XOR-swizzled so frag ds_read_b128 banks are uniformly spread.
// ---------------------------------------------------------------------------
__global__ __launch_bounds__(256) void gemm_bf16x3(
    const unsigned short* __restrict__ Abase,
    const unsigned short* __restrict__ Wtbase, float* __restrict__ Cbase,
    const float* __restrict__ bb0, const float* __restrict__ bb1,
    const float* __restrict__ bb2) {
  __shared__ s16x8 As[512];
  __shared__ s16x8 Bs[512];
  int z = blockIdx.z;
  const unsigned short* A = Abase + (size_t)z * XS_SLAB;
  const unsigned short* Wt = Wtbase + (size_t)z * WT_SLAB;
  float* C = Cbase + (size_t)z * F_SLAB;
  const float* bias = z == 0 ? bb0 : (z == 1 ? bb1 : bb2);

  const int t = threadIdx.x;
  const int lane = t & 63, wave = t >> 6;
  const int wm = wave & 1, wn = wave >> 1;
  const int bm = blockIdx.y * 128, bn = blockIdx.x * 128;

  f32x4 acc[4][4] = {};

  // the 2 A-slots + 2 B-slots this thread stages (slot -> (row, src chunk))
  const int s0 = t, s1 = t + 256;
  const int r0 = s0 >> 2, c0 = (s0 & 3) ^ ((r0 >> 1) & 3);
  const int r1 = s1 >> 2, c1 = (s1 & 3) ^ ((r1 >> 1) & 3);
  const unsigned short* A0 = A + (size_t)(bm + r0) * 2048 + c0 * 8;
  const unsigned short* A1 = A + (size_t)(bm + r1) * 2048 + c1 * 8;
  const unsigned short* B0 = Wt + (size_t)(bn + r0) * 2048 + c0 * 8;
  const unsigned short* B1 = Wt + (size_t)(bn + r1) * 2048 + c1 * 8;

  // preload kb = 0
  s16x8 va0 = *(const s16x8*)(A0);
  s16x8 va1 = *(const s16x8*)(A1);
  s16x8 vb0 = *(const s16x8*)(B0);
  s16x8 vb1 = *(const s16x8*)(B1);

  const int m15 = lane & 15, q = lane >> 4;

  for (int kb = 0; kb < 3072; kb += 32) {
    __syncthreads();
    As[s0] = va0; As[s1] = va1;
    Bs[s0] = vb0; Bs[s1] = vb1;
    __syncthreads();

    // prefetch next K-tile while MFMAs run
    int kb2 = kb + 32;
    if (kb2 >= 3072) kb2 = 0;
    int asrc = kb2 < 1024 ? kb2 : kb2 - 1024;
    int wsrc = kb2 < 2048 ? kb2 : kb2 - 2048;
    va0 = *(const s16x8*)(A0 + asrc);
    va1 = *(const s16x8*)(A1 + asrc);
    vb0 = *(const s16x8*)(B0 + wsrc);
    vb1 = *(const s16x8*)(B1 + wsrc);

    s16x8 af[4], bf[4];
#pragma unroll
    for (int mt = 0; mt < 4; ++mt) {
      int r = wm * 64 + mt * 16 + m15;
      af[mt] = As[r * 4 + (q ^ ((r >> 1) & 3))];
    }
#pragma unroll
    for (int nt = 0; nt < 4; ++nt) {
      int r = wn * 64 + nt * 16 + m15;
      bf[nt] = Bs[r * 4 + (q ^ ((r >> 1) & 3))];
    }
#pragma unroll
    for (int mt = 0; mt < 4; ++mt)
#pragma unroll
      for (int nt = 0; nt < 4; ++nt)
        acc[mt][nt] = __builtin_amdgcn_mfma_f32_16x16x32_bf16(
            af[mt], bf[nt], acc[mt][nt], 0, 0, 0);
  }

  // epilogue: D row = mt*16 + (lane>>4)*4 + i, col = nt*16 + (lane&15)
#pragma unroll
  for (int nt = 0; nt < 4; ++nt) {
    int col = bn + wn * 64 + nt * 16 + m15;
    float bv = bias[col];
#pragma unroll
    for (int mt = 0; mt < 4; ++mt) {
      int rowb = bm + wm * 64 + mt * 16 + q * 4;
#pragma unroll
      for (int i = 0; i < 4; ++i)
        C[(size_t)(rowb + i) * 1024 + col] = acc[mt][nt][i] + bv;
    }
  }
}

// ---------------------------------------------------------------------------
// Fused attention: per block = one (b,h) x 16-query tile.
// Stage 1: banded QK^T/8 into LDS tile. Stage 2a: per-row softmax, write
// normalized probs (zeros out-of-band) back to LDS. Stage 2b: copy full
// 2048-wide rows (probs+zeros) to the attn output. Stage 3: PV from LDS probs
// (zero cols make masking free), write AO.
// ---------------------------------------------------------------------------
constexpr int SW = 532;  // LDS row stride (floats); 532%32=20 spreads banks
__global__ __launch_bounds__(256) void attn_fused(
    const float* __restrict__ Qp, const float* __restrict__ Kp,
    const float* __restrict__ Vp, float* __restrict__ attn,
    float* __restrict__ AO) {
  __shared__ float S[16 * SW + 64];  // +64 pad: speculated reads stay in-bounds
  const int t = threadIdx.x;
  int bid = blockIdx.x;          // B*H*(S/16) = 4096
  int qt = bid & 127;            // S/16 = 128
  int h = (bid >> 7) & 15;
  int b = bid >> 11;
  int q0 = qt * 16;
  int jlo = q0 - WINw; if (jlo < 0) jlo = 0;
  int jhi = q0 + 15 + WINw; if (jhi > Ss - 1) jhi = Ss - 1;
  int ncols = jhi - jlo + 1;  // <= 528, multiple of 4

  // ---- stage 1: scores -> LDS ----
  {
    const int qa = t & 15, kq = t >> 4;
    f32x4 qr[16];
    const float* qb = &Qp[((size_t)(b * Ss + q0 + qa)) * Dd + h * 64];
#pragma unroll
    for (int i = 0; i < 16; ++i) qr[i] = *(const f32x4*)&qb[i * 4];
    for (int jc = jlo; jc <= jhi; jc += 64) {
      int col0 = jc - jlo + kq * 4;
      if (col0 < ncols) {
        const float* kb = &Kp[((size_t)(b * Ss + jc + kq * 4)) * Dd + h * 64];
        float s0 = 0.f, s1 = 0.f, s2 = 0.f, s3 = 0.f;
#pragma unroll
        for (int d4 = 0; d4 < 16; ++d4) {
          f32x4 qv = qr[d4];
          f32x4 k0v = *(const f32x4*)&kb[d4 * 4];
          f32x4 k1v = *(const f32x4*)&kb[Dd + d4 * 4];
          f32x4 k2v = *(const f32x4*)&kb[2 * Dd + d4 * 4];
          f32x4 k3v = *(const f32x4*)&kb[3 * Dd + d4 * 4];
          s0 += qv[0] * k0v[0] + qv[1] * k0v[1] + qv[2] * k0v[2] + qv[3] * k0v[3];
          s1 += qv[0] * k1v[0] + qv[1] * k1v[1] + qv[2] * k1v[2] + qv[3] * k1v[3];
          s2 += qv[0] * k2v[0] + qv[1] * k2v[1] + qv[2] * k2v[2] + qv[3] * k2v[3];
          s3 += qv[0] * k3v[0] + qv[1] * k3v[1] + qv[2] * k3v[2] + qv[3] * k3v[3];
        }
        f32x4 sv = {s0 * 0.125f, s1 * 0.125f, s2 * 0.125f, s3 * 0.125f};
        *(f32x4*)&S[qa * SW + col0] = sv;
      }
    }
  }
  __syncthreads();

  // ---- stage 2a: softmax per row, normalized probs (+zeros) back to LDS ----
  {
    const int wv = t >> 6, lane = t & 63;
#pragma unroll
    for (int ri = 0; ri < 4; ++ri) {
      int r = wv * 4 + ri;
      int qq = q0 + r;
      int lo = qq - WINw; if (lo < 0) lo = 0;
      int hi = qq + WINw; if (hi > Ss - 1) hi = Ss - 1;
      float sv[9]; bool ib[9];
      float m = -1e30f;
#pragma unroll
      for (int k2 = 0; k2 < 9; ++k2) {
        int c = k2 * 64 + lane;
        int j = jlo + c;
        bool inb = (j >= lo) && (j <= hi);
        ib[k2] = inb;
        float vv = inb ? S[r * SW + c] : -1e30f;
        sv[k2] = vv;
        m = fmaxf(m, vv);
      }
#pragma unroll
      for (int off = 32; off; off >>= 1) m = fmaxf(m, __shfl_xor(m, off, 64));
      float e[9]; float l = 0.f;
#pragma unroll
      for (int k2 = 0; k2 < 9; ++k2) { e[k2] = __expf(sv[k2] - m); l += e[k2]; }
#pragma unroll
      for (int off = 32; off; off >>= 1) l += __shfl_xor(l, off, 64);
      float inv = 1.f / l;
#pragma unroll
      for (int k2 = 0; k2 < 9; ++k2) {
        int c = k2 * 64 + lane;
        if (c < SW) S[r * SW + c] = ib[k2] ? e[k2] * inv : 0.f;
      }
    }
  }
  __syncthreads();

  // ---- stage 2b: full attn rows (probs + zeros) to global ----
  {
    int r = t >> 4, lane16 = t & 15;
    int qq = q0 + r;
    float* arow = attn + ((size_t)((b * Hh + h) * Ss + qq)) * Ss;
#pragma unroll
    for (int i = 0; i < 32; ++i) {
      int col = (i * 16 + lane16) * 4;
      int c = col - jlo;
      int cc = c; if (cc < 0) cc = 0; if (cc > 528) cc = 528;
      f32x4 v = *(const f32x4*)&S[r * SW + cc];
      if (c != cc) v = (f32x4){0.f, 0.f, 0.f, 0.f};
      *(f32x4*)&arow[col] = v;
    }
  }

  // ---- stage 3: PV from LDS probs ----
  {
    int dg = t & 15, qp = t >> 4;
    f32x4 a0 = {0.f, 0.f, 0.f, 0.f};
    const float* Vb = &Vp[(size_t)(b * Ss) * Dd + h * 64 + dg * 4];
    for (int jc = jlo; jc <= jhi; jc += 4) {
      int c = jc - jlo;
      f32x4 p = *(const f32x4*)&S[qp * SW + c];
      const float* vb = Vb + (size_t)jc * Dd;
      f32x4 v0 = *(const f32x4*)vb;
      f32x4 v1 = *(const f32x4*)(vb + Dd);
      f32x4 v2 = *(const f32x4*)(vb + 2 * Dd);
      f32x4 v3 = *(const f32x4*)(vb + 3 * Dd);
      a0 += p[0] * v0; a0 += p[1] * v1; a0 += p[2] * v2; a0 += p[3] * v3;
    }
    *(f32x4*)&AO[((size_t)(b * Ss + q0 + qp)) * Dd + h * 64 + dg * 4] = a0;
  }
}

// ---------------------------------------------------------------------------
extern "C" void kernel_launch(void* const* d_in, const int* in_sizes, int n_in,
                              void* d_out, int out_size, void* d_ws,
                              size_t ws_size, hipStream_t stream) {
  const float* q  = (const float*)d_in[0];
  const float* k  = (const float*)d_in[1];
  const float* v  = (const float*)d_in[2];
  const float* Wq = (const float*)d_in[3];
  const float* bq = (const float*)d_in[4];
  const float* Wk = (const float*)d_in[5];
  const float* bk = (const float*)d_in[6];
  const float* Wv = (const float*)d_in[7];
  const float* bv = (const float*)d_in[8];
  const float* Wo = (const float*)d_in[9];
  const float* bo = (const float*)d_in[10];

  float* out = (float*)d_out;
  float* attn = out + (size_t)Bb * Ss * Dd;

  unsigned short* Xs = (unsigned short*)d_ws;                 // 3 * 16 MB
  unsigned short* Wt = Xs + 3 * XS_SLAB;                      // 4 * 4 MB
  float* Qp = (float*)(Wt + 4 * WT_SLAB);                     // 16 MB
  float* Kp = Qp + F_SLAB;
  float* Vp = Kp + F_SLAB;
  float* AO = Vp + F_SLAB;

  // convert inputs and weights to bf16 hi/lo
  hipLaunchKernelGGL(convert_x, dim3(4096, 1, 3), dim3(256), 0, stream, q, k, v, Xs);
  hipLaunchKernelGGL(convert_w, dim3(16, 16, 4), dim3(256), 0, stream, Wq, Wk, Wv, Wo, Wt);
  // batched q/k/v projections
  hipLaunchKernelGGL(gemm_bf16x3, dim3(8, 32, 3), dim3(256), 0, stream,
                     Xs, Wt, Qp, bq, bk, bv);
  // fused banded attention (scores + softmax + attn-output + PV)
  hipLaunchKernelGGL(attn_fused, dim3(Bb * Hh * (Ss / 16)), dim3(256), 0, stream,
                     Qp, Kp, Vp, attn, AO);
  // output projection
  hipLaunchKernelGGL(convert_x, dim3(4096, 1, 1), dim3(256), 0, stream, AO, AO, AO, Xs);
  hipLaunchKernelGGL(gemm_bf16x3, dim3(8, 32, 1), dim3(256), 0, stream,
                     Xs, Wt + 3 * WT_SLAB, out, bo, bo, bo);
}

// Round 3
// 821.355 us; speedup vs baseline: 2.1364x; 1.6953x over previous
//
#include <hip/hip_runtime.h>

// B=2, S=2048, D=1024, H=16, d_k=64, WINDOW=256
// d_out = out [B,S,D] fp32  ++  attn [B,H,S,S] fp32
// ws (112 MB): Xs bf16 3x[4096x2048] | XsAO bf16 [4096x2048] | Wt bf16 4x[1024x2048]
//              | Qb,Kb,Vb bf16 [4096x1024] | Vt bf16 [B,H,64,2048]

constexpr int Bb = 2, Ss = 2048, Dd = 1024, Hh = 16, WINw = 256;
constexpr size_t XS_SLAB = (size_t)4096 * 2048;  // bf16 elems
constexpr size_t WT_SLAB = (size_t)1024 * 2048;  // bf16 elems
constexpr size_t QB_SLAB = (size_t)4096 * 1024;  // bf16 elems

typedef short s16x8 __attribute__((ext_vector_type(8)));
typedef float f32x4 __attribute__((ext_vector_type(4)));

__device__ inline unsigned short f2bf(float x) {
  unsigned u = __float_as_uint(x);
  u += 0x7fff + ((u >> 16) & 1);  // RNE
  return (unsigned short)(u >> 16);
}
__device__ inline float bf2f(unsigned short h) {
  return __uint_as_float(((unsigned)h) << 16);
}

// ---------------------------------------------------------------------------
// fp32 [4096x1024] -> bf16 split [4096x2048] = [hi | lo]; z selects source.
// ---------------------------------------------------------------------------
__global__ __launch_bounds__(256) void convert_x(
    const float* __restrict__ x0, const float* __restrict__ x1,
    const float* __restrict__ x2, unsigned short* __restrict__ Xs) {
  int z = blockIdx.z;
  const float* src = z == 0 ? x0 : (z == 1 ? x1 : x2);
  unsigned short* dst = Xs + (size_t)z * XS_SLAB;
  size_t idx = ((size_t)blockIdx.x * 256 + threadIdx.x) * 4;
  int r = (int)(idx >> 10);
  int c = (int)(idx & 1023);
  f32x4 v = *(const f32x4*)&src[idx];
  unsigned short hi[4], lo[4];
#pragma unroll
  for (int i = 0; i < 4; ++i) {
    float vi = v[i];
    hi[i] = f2bf(vi);
    lo[i] = f2bf(vi - bf2f(hi[i]));
  }
  ushort4 h4 = {hi[0], hi[1], hi[2], hi[3]};
  ushort4 l4 = {lo[0], lo[1], lo[2], lo[3]};
  *(ushort4*)&dst[(size_t)r * 2048 + c] = h4;
  *(ushort4*)&dst[(size_t)r * 2048 + 1024 + c] = l4;
}

// ---------------------------------------------------------------------------
// W [1024x1024] fp32 -> Wt bf16 [n][2048] = [W_hi^T | W_lo^T] (transposed).
// ---------------------------------------------------------------------------
__global__ __launch_bounds__(256) void convert_w(
    const float* __restrict__ w0, const float* __restrict__ w1,
    const float* __restrict__ w2, const float* __restrict__ w3,
    unsigned short* __restrict__ Wt) {
  __shared__ float T[64][65];
  int z = blockIdx.z;
  const float* W = z == 0 ? w0 : (z == 1 ? w1 : (z == 2 ? w2 : w3));
  unsigned short* dst = Wt + (size_t)z * WT_SLAB;
  int k0 = blockIdx.y * 64, n0 = blockIdx.x * 64;
  int t = threadIdx.x;
#pragma unroll
  for (int i = 0; i < 4; ++i) {
    int row = (t >> 4) + i * 16;
    int c4 = (t & 15) * 4;
    f32x4 v = *(const f32x4*)&W[(size_t)(k0 + row) * 1024 + n0 + c4];
    T[row][c4 + 0] = v[0]; T[row][c4 + 1] = v[1];
    T[row][c4 + 2] = v[2]; T[row][c4 + 3] = v[3];
  }
  __syncthreads();
  int n = t >> 2;
  int kc = (t & 3) * 16;
  unsigned short hi[16], lo[16];
#pragma unroll
  for (int j = 0; j < 16; ++j) {
    float x = T[kc + j][n];
    hi[j] = f2bf(x);
    lo[j] = f2bf(x - bf2f(hi[j]));
  }
  size_t base = (size_t)(n0 + n) * 2048 + k0 + kc;
#pragma unroll
  for (int j4 = 0; j4 < 4; ++j4) {
    ushort4 h4 = {hi[j4 * 4], hi[j4 * 4 + 1], hi[j4 * 4 + 2], hi[j4 * 4 + 3]};
    ushort4 l4 = {lo[j4 * 4], lo[j4 * 4 + 1], lo[j4 * 4 + 2], lo[j4 * 4 + 3]};
    *(ushort4*)&dst[base + j4 * 4] = h4;
    *(ushort4*)&dst[base + 1024 + j4 * 4] = l4;
  }
}

// ---------------------------------------------------------------------------
// C[4096x1024] = Abig[4096x3072] @ Wbig[3072x1024] + bias, bf16x3 split.
// F32OUT=1: fp32 C (final out-proj). F32OUT=0: bf16 C (QKV; z=0 scaled 1/8).
// ---------------------------------------------------------------------------
template <int F32OUT>
__global__ __launch_bounds__(256) void gemm_bf16x3(
    const unsigned short* __restrict__ Abase,
    const unsigned short* __restrict__ Wtbase, void* __restrict__ Cbase,
    const float* __restrict__ bb0, const float* __restrict__ bb1,
    const float* __restrict__ bb2) {
  __shared__ s16x8 As[512];
  __shared__ s16x8 Bs[512];
  int z = blockIdx.z;
  const unsigned short* A = Abase + (size_t)z * XS_SLAB;
  const unsigned short* Wt = Wtbase + (size_t)z * WT_SLAB;
  const float* bias = z == 0 ? bb0 : (z == 1 ? bb1 : bb2);
  const float scl = (!F32OUT && z == 0) ? 0.125f : 1.0f;

  const int t = threadIdx.x;
  const int lane = t & 63, wave = t >> 6;
  const int wm = wave & 1, wn = wave >> 1;
  const int bm = blockIdx.y * 128, bn = blockIdx.x * 128;

  f32x4 acc[4][4] = {};

  const int s0 = t, s1 = t + 256;
  const int r0 = s0 >> 2, c0 = (s0 & 3) ^ ((r0 >> 1) & 3);
  const int r1 = s1 >> 2, c1 = (s1 & 3) ^ ((r1 >> 1) & 3);
  const unsigned short* A0 = A + (size_t)(bm + r0) * 2048 + c0 * 8;
  const unsigned short* A1 = A + (size_t)(bm + r1) * 2048 + c1 * 8;
  const unsigned short* B0 = Wt + (size_t)(bn + r0) * 2048 + c0 * 8;
  const unsigned short* B1 = Wt + (size_t)(bn + r1) * 2048 + c1 * 8;

  s16x8 va0 = *(const s16x8*)(A0);
  s16x8 va1 = *(const s16x8*)(A1);
  s16x8 vb0 = *(const s16x8*)(B0);
  s16x8 vb1 = *(const s16x8*)(B1);

  const int m15 = lane & 15, q = lane >> 4;

  for (int kb = 0; kb < 3072; kb += 32) {
    __syncthreads();
    As[s0] = va0; As[s1] = va1;
    Bs[s0] = vb0; Bs[s1] = vb1;
    __syncthreads();

    int kb2 = kb + 32;
    if (kb2 >= 3072) kb2 = 0;
    int asrc = kb2 < 1024 ? kb2 : kb2 - 1024;
    int wsrc = kb2 < 2048 ? kb2 : kb2 - 2048;
    va0 = *(const s16x8*)(A0 + asrc);
    va1 = *(const s16x8*)(A1 + asrc);
    vb0 = *(const s16x8*)(B0 + wsrc);
    vb1 = *(const s16x8*)(B1 + wsrc);

    s16x8 af[4], bf[4];
#pragma unroll
    for (int mt = 0; mt < 4; ++mt) {
      int r = wm * 64 + mt * 16 + m15;
      af[mt] = As[r * 4 + (q ^ ((r >> 1) & 3))];
    }
#pragma unroll
    for (int nt = 0; nt < 4; ++nt) {
      int r = wn * 64 + nt * 16 + m15;
      bf[nt] = Bs[r * 4 + (q ^ ((r >> 1) & 3))];
    }
#pragma unroll
    for (int mt = 0; mt < 4; ++mt)
#pragma unroll
      for (int nt = 0; nt < 4; ++nt)
        acc[mt][nt] = __builtin_amdgcn_mfma_f32_16x16x32_bf16(
            af[mt], bf[nt], acc[mt][nt], 0, 0, 0);
  }

#pragma unroll
  for (int nt = 0; nt < 4; ++nt) {
    int col = bn + wn * 64 + nt * 16 + m15;
    float bv = bias[col];
#pragma unroll
    for (int mt = 0; mt < 4; ++mt) {
      int rowb = bm + wm * 64 + mt * 16 + q * 4;
#pragma unroll
      for (int i = 0; i < 4; ++i) {
        float val = (acc[mt][nt][i] + bv) * scl;
        if (F32OUT) {
          ((float*)Cbase)[(size_t)(rowb + i) * 1024 + col] = val;
        } else {
          ((unsigned short*)Cbase + (size_t)z * QB_SLAB)
              [(size_t)(rowb + i) * 1024 + col] = f2bf(val);
        }
      }
    }
  }
}

// ---------------------------------------------------------------------------
// Vb [4096][1024] bf16 -> Vt [b][h][d][s] bf16 (per-head transposed).
// ---------------------------------------------------------------------------
__global__ __launch_bounds__(256) void transpose_v(
    const unsigned short* __restrict__ Vb, unsigned short* __restrict__ Vt) {
  __shared__ unsigned short T[64][88];
  const int b = blockIdx.z, h = blockIdx.y, s0 = blockIdx.x * 64;
  const int t = threadIdx.x;
  {
    int row = t >> 2, part = t & 3;
    const unsigned short* src =
        Vb + (size_t)(b * Ss + s0 + row) * 1024 + h * 64 + part * 16;
    s16x8 v0 = *(const s16x8*)src;
    s16x8 v1 = *(const s16x8*)(src + 8);
    *(s16x8*)&T[row][part * 16] = v0;
    *(s16x8*)&T[row][part * 16 + 8] = v1;
  }
  __syncthreads();
  {
    int d = t & 63, sw = t >> 6;
    unsigned short tmp[16];
#pragma unroll
    for (int i = 0; i < 16; ++i) tmp[i] = T[sw * 16 + i][d];
    unsigned short* dst =
        Vt + ((size_t)((b * Hh + h) * 64 + d)) * 2048 + s0 + sw * 16;
    *(s16x8*)dst = *(const s16x8*)&tmp[0];
    *(s16x8*)(dst + 8) = *(const s16x8*)&tmp[8];
  }
}

// ---------------------------------------------------------------------------
// Fused attention v3: per block = one (b,h) x 16-query tile, 4 waves.
// S1: scores via MFMA (Q pre-scaled 1/8) -> LDS P fp32.
// S2: per-row softmax; write full 2048-wide attn rows; probs back to LDS.
// S3: PV via MFMA (A = P rows cvt bf16 from LDS, B = Vt rows contiguous);
//     epilogue writes AO directly as hi/lo bf16 (Xs layout) for out-proj.
// ---------------------------------------------------------------------------
constexpr int SW3 = 556;  // f32 stride: 556%32=12 -> <=2-way banks; 16B-aligned
__global__ __launch_bounds__(256) void attn_v3(
    const unsigned short* __restrict__ Qb, const unsigned short* __restrict__ Kb,
    const unsigned short* __restrict__ Vt, float* __restrict__ attn,
    unsigned short* __restrict__ XsAO) {
  __shared__ float P[16 * SW3];  // 35.6 KB
  const int t = threadIdx.x;
  const int lane = t & 63, wave = t >> 6;
  const int m15 = lane & 15, quad = lane >> 4;
  const int bid = blockIdx.x;
  const int qt = bid & 127, h = (bid >> 7) & 15, b = bid >> 11;
  const int q0 = qt * 16;
  int jlo = q0 - WINw; if (jlo < 0) jlo = 0;
  int jhi = q0 + 15 + WINw; if (jhi > Ss - 1) jhi = Ss - 1;
  const int ncols = jhi - jlo + 1;  // always a multiple of 16
  const int ntiles = ncols >> 4;

  // ---- stage 1: scores via MFMA -> P ----
  {
    const unsigned short* qrow =
        Qb + (size_t)(b * Ss + q0 + m15) * 1024 + h * 64 + quad * 8;
    s16x8 aq0 = *(const s16x8*)qrow;
    s16x8 aq1 = *(const s16x8*)(qrow + 32);
    for (int nt = wave; nt < ntiles; nt += 4) {
      const unsigned short* krow =
          Kb + (size_t)(b * Ss + jlo + nt * 16 + m15) * 1024 + h * 64 + quad * 8;
      s16x8 b0 = *(const s16x8*)krow;
      s16x8 b1 = *(const s16x8*)(krow + 32);
      f32x4 c = {0.f, 0.f, 0.f, 0.f};
      c = __builtin_amdgcn_mfma_f32_16x16x32_bf16(aq0, b0, c, 0, 0, 0);
      c = __builtin_amdgcn_mfma_f32_16x16x32_bf16(aq1, b1, c, 0, 0, 0);
      float* pp = &P[(quad * 4) * SW3 + nt * 16 + m15];
#pragma unroll
      for (int i = 0; i < 4; ++i) pp[i * SW3] = c[i];
    }
  }
  __syncthreads();

  // ---- stage 2: softmax + attn row write + probs -> LDS ----
  {
#pragma unroll
    for (int ri = 0; ri < 4; ++ri) {
      const int r = wave * 4 + ri;
      const int qq = q0 + r;
      int lo = qq - WINw; if (lo < 0) lo = 0;
      int hi = qq + WINw; if (hi > Ss - 1) hi = Ss - 1;
      const int clo = lo - jlo, chi = hi - jlo;
      float sv[9];
      bool ib[9];
      float m = -1e30f;
#pragma unroll
      for (int k2 = 0; k2 < 9; ++k2) {
        int c = k2 * 64 + lane;
        bool inb = (c >= clo) && (c <= chi);
        ib[k2] = inb;
        float vv = inb ? P[r * SW3 + c] : -1e30f;
        sv[k2] = vv;
        m = fmaxf(m, vv);
      }
#pragma unroll
      for (int off = 32; off; off >>= 1) m = fmaxf(m, __shfl_xor(m, off, 64));
      float e[9], l = 0.f;
#pragma unroll
      for (int k2 = 0; k2 < 9; ++k2) { e[k2] = __expf(sv[k2] - m); l += e[k2]; }
#pragma unroll
      for (int off = 32; off; off >>= 1) l += __shfl_xor(l, off, 64);
      const float inv = 1.f / l;
#pragma unroll
      for (int k2 = 0; k2 < 9; ++k2) {
        int c = k2 * 64 + lane;
        if (c < 544) P[r * SW3 + c] = ib[k2] ? e[k2] * inv : 0.f;
      }
      float* arow = attn + ((size_t)((b * Hh + h) * Ss + qq)) * Ss;
#pragma unroll
      for (int i = 0; i < 8; ++i) {
        int col = i * 256 + lane * 4;
        int c = col - jlo;
        f32x4 v = {0.f, 0.f, 0.f, 0.f};
        if (c >= 0 && c <= 540) v = *(const f32x4*)&P[r * SW3 + c];
        *(f32x4*)&arow[col] = v;
      }
    }
  }
  __syncthreads();

  // ---- stage 3: PV via MFMA; wave = d-tile ----
  {
    const int ntk = (ncols + 31) >> 5;
    const unsigned short* vtrow =
        Vt + ((size_t)((b * Hh + h) * 64 + wave * 16 + m15)) * 2048 + jlo +
        quad * 8;
    f32x4 o = {0.f, 0.f, 0.f, 0.f};
    for (int ks = 0; ks < ntk; ++ks) {
      const float* pa = &P[m15 * SW3 + ks * 32 + quad * 8];
      f32x4 p0 = *(const f32x4*)pa;
      f32x4 p1 = *(const f32x4*)(pa + 4);
      s16x8 af;
#pragma unroll
      for (int i = 0; i < 4; ++i) af[i] = (short)f2bf(p0[i]);
#pragma unroll
      for (int i = 0; i < 4; ++i) af[4 + i] = (short)f2bf(p1[i]);
      s16x8 bf = *(const s16x8*)(vtrow + ks * 32);
      o = __builtin_amdgcn_mfma_f32_16x16x32_bf16(af, bf, o, 0, 0, 0);
    }
    const int dcol = h * 64 + wave * 16 + m15;
#pragma unroll
    for (int i = 0; i < 4; ++i) {
      int row = q0 + quad * 4 + i;
      unsigned short hi = f2bf(o[i]);
      unsigned short lo = f2bf(o[i] - bf2f(hi));
      unsigned short* dst = XsAO + (size_t)(b * Ss + row) * 2048 + dcol;
      dst[0] = hi;
      dst[1024] = lo;
    }
  }
}

// ---------------------------------------------------------------------------
extern "C" void kernel_launch(void* const* d_in, const int* in_sizes, int n_in,
                              void* d_out, int out_size, void* d_ws,
                              size_t ws_size, hipStream_t stream) {
  const float* q  = (const float*)d_in[0];
  const float* k  = (const float*)d_in[1];
  const float* v  = (const float*)d_in[2];
  const float* Wq = (const float*)d_in[3];
  const float* bq = (const float*)d_in[4];
  const float* Wk = (const float*)d_in[5];
  const float* bk = (const float*)d_in[6];
  const float* Wv = (const float*)d_in[7];
  const float* bv = (const float*)d_in[8];
  const float* Wo = (const float*)d_in[9];
  const float* bo = (const float*)d_in[10];

  float* out = (float*)d_out;
  float* attn = out + (size_t)Bb * Ss * Dd;

  unsigned short* Xs   = (unsigned short*)d_ws;   // 48 MB
  unsigned short* XsAO = Xs + 3 * XS_SLAB;        // 16 MB
  unsigned short* Wt   = XsAO + XS_SLAB;          // 16 MB
  unsigned short* Qb   = Wt + 4 * WT_SLAB;        // 8 MB
  unsigned short* Kb   = Qb + QB_SLAB;            // 8 MB
  unsigned short* Vb   = Kb + QB_SLAB;            // 8 MB
  unsigned short* Vt   = Vb + QB_SLAB;            // 8 MB (+slack after)

  hipLaunchKernelGGL(convert_x, dim3(4096, 1, 3), dim3(256), 0, stream,
                     q, k, v, Xs);
  hipLaunchKernelGGL(convert_w, dim3(16, 16, 4), dim3(256), 0, stream,
                     Wq, Wk, Wv, Wo, Wt);
  hipLaunchKernelGGL((gemm_bf16x3<0>), dim3(8, 32, 3), dim3(256), 0, stream,
                     Xs, Wt, (void*)Qb, bq, bk, bv);
  hipLaunchKernelGGL(transpose_v, dim3(32, 16, 2), dim3(256), 0, stream,
                     Vb, Vt);
  hipLaunchKernelGGL(attn_v3, dim3(Bb * Hh * (Ss / 16)), dim3(256), 0, stream,
                     Qb, Kb, Vt, attn, XsAO);
  hipLaunchKernelGGL((gemm_bf16x3<1>), dim3(8, 32, 1), dim3(256), 0, stream,
                     XsAO, Wt + 3 * WT_SLAB, (void*)out, bo, bo, bo);
}